// Round 1
// baseline (2638.417 us; speedup 1.0000x reference)
//
#include <hip/hip_runtime.h>
#include <cstdint>
#include <cstddef>

// ---------------------------------------------------------------------------
// MaxK-GIN: h=relu(x@W_in+b); 2x { h=h@W+b; maxk16; scatter-add over edges;
//           h=(1+eps)*sparse+neigh }; out = h@W_out+b_out
// ---------------------------------------------------------------------------

// ---------------- GEMM: Y[r, 0:NOUT] = X[r, 0:128] @ W + bias (opt relu) ----
// W staged fully in LDS; X tile staged in LDS; each thread computes 4 rows x 4 cols.
template <int NOUT, bool RELU>
__global__ __launch_bounds__(256, 2) void gemm_kernel(
    const float* __restrict__ X, const float* __restrict__ W,
    const float* __restrict__ bias, float* __restrict__ Y, int nrows,
    int ntiles) {
  constexpr int CT = NOUT / 4;    // threads covering the col dim (4 cols each)
  constexpr int RG = 256 / CT;    // row groups per block
  constexpr int RPB = RG * 4;     // rows per block tile
  constexpr int XPAD = (NOUT == 64) ? 4 : 0;  // break 4-way bank conflict
  constexpr int XLD = 128 + XPAD;

  __shared__ float Wlds[128 * NOUT];
  __shared__ float Xlds[RPB * XLD];

  const int tid = threadIdx.x;

  // cooperative load of W (128 x NOUT), coalesced float4
  for (int f = tid; f < 128 * NOUT / 4; f += 256) {
    ((float4*)Wlds)[f] = ((const float4*)W)[f];
  }

  const int c4 = (tid % CT) * 4;
  const int r0 = (tid / CT) * 4;
  const float4 bv = *(const float4*)&bias[c4];

  for (int tile = blockIdx.x; tile < ntiles; tile += gridDim.x) {
    const int row0 = tile * RPB;
    __syncthreads();  // W ready (iter 0); previous compute done (iter >0)

    // stage X tile (RPB x 128), coalesced float4
    for (int f = tid; f < RPB * 32; f += 256) {
      const int r = f >> 5;
      const int cq = (f & 31) * 4;
      const int grow = row0 + r;
      float4 xv = make_float4(0.f, 0.f, 0.f, 0.f);
      if (grow < nrows) xv = *(const float4*)&X[(size_t)grow * 128 + cq];
      *(float4*)&Xlds[r * XLD + cq] = xv;
    }
    __syncthreads();

    float4 acc[4];
#pragma unroll
    for (int j = 0; j < 4; ++j) acc[j] = make_float4(0.f, 0.f, 0.f, 0.f);

#pragma unroll 4
    for (int k = 0; k < 128; k += 4) {
      const float4 w0 = *(const float4*)&Wlds[(k + 0) * NOUT + c4];
      const float4 w1 = *(const float4*)&Wlds[(k + 1) * NOUT + c4];
      const float4 w2 = *(const float4*)&Wlds[(k + 2) * NOUT + c4];
      const float4 w3 = *(const float4*)&Wlds[(k + 3) * NOUT + c4];
#pragma unroll
      for (int j = 0; j < 4; ++j) {
        const float4 xv = *(const float4*)&Xlds[(r0 + j) * XLD + k];
        acc[j].x += xv.x * w0.x + xv.y * w1.x + xv.z * w2.x + xv.w * w3.x;
        acc[j].y += xv.x * w0.y + xv.y * w1.y + xv.z * w2.y + xv.w * w3.y;
        acc[j].z += xv.x * w0.z + xv.y * w1.z + xv.z * w2.z + xv.w * w3.z;
        acc[j].w += xv.x * w0.w + xv.y * w1.w + xv.z * w2.w + xv.w * w3.w;
      }
    }

#pragma unroll
    for (int j = 0; j < 4; ++j) {
      const int grow = row0 + r0 + j;
      if (grow < nrows) {
        float4 o = acc[j];
        o.x += bv.x; o.y += bv.y; o.z += bv.z; o.w += bv.w;
        if (RELU) {
          o.x = fmaxf(o.x, 0.f); o.y = fmaxf(o.y, 0.f);
          o.z = fmaxf(o.z, 0.f); o.w = fmaxf(o.w, 0.f);
        }
        *(float4*)&Y[(size_t)grow * NOUT + c4] = o;
      }
    }
  }
}

// ---------------- MaxK: top-16 of 128 per row -------------------------------
// wave per row; iterative max extraction (ties -> lowest index, matching
// jax.lax.top_k). Writes compressed (vals, idx) and dense (1+eps)*h_sparse.
__global__ __launch_bounds__(256) void maxk_kernel(
    const float* __restrict__ T, const float* __restrict__ eps_p,
    float* __restrict__ vals, int* __restrict__ idxo, float* __restrict__ Hout,
    int nrows) {
  const int lane = threadIdx.x & 63;
  const int wid = threadIdx.x >> 6;
  const float e = 1.0f + *eps_p;

  for (int row = blockIdx.x * 4 + wid; row < nrows; row += gridDim.x * 4) {
    const float o0 = T[(size_t)row * 128 + lane];
    const float o1 = T[(size_t)row * 128 + 64 + lane];
    float v0 = o0, v1 = o1;

#pragma unroll
    for (int it = 0; it < 16; ++it) {
      float m = fmaxf(v0, v1);
#pragma unroll
      for (int off = 32; off; off >>= 1) m = fmaxf(m, __shfl_xor(m, off));
      const unsigned long long b0 = __ballot(v0 == m);
      int sel;
      if (b0) {
        sel = __ffsll((unsigned long long)b0) - 1;
        if (lane == sel) v0 = -INFINITY;
      } else {
        const unsigned long long b1 = __ballot(v1 == m);
        sel = __ffsll((unsigned long long)b1) - 1;
        if (lane == sel) v1 = -INFINITY;
        sel += 64;
      }
      if (lane == 0) {
        vals[(size_t)row * 16 + it] = m;
        idxo[(size_t)row * 16 + it] = sel;
      }
    }
    // dense (1+eps)*h_sparse seed for the aggregation buffer
    Hout[(size_t)row * 128 + lane] = (v0 == -INFINITY) ? o0 * e : 0.0f;
    Hout[(size_t)row * 128 + 64 + lane] = (v1 == -INFINITY) ? o1 * e : 0.0f;
  }
}

// ---------------- Edge scatter: H[dst] += h_sparse[src] (compressed) --------
// 4 lanes per edge, each lane handles 4 of the 16 nonzeros.
__global__ __launch_bounds__(256) void scatter_kernel(
    const int* __restrict__ src, const int* __restrict__ dst,
    const float* __restrict__ vals, const int* __restrict__ idx,
    float* __restrict__ H, int nedges) {
  const int t = blockIdx.x * 256 + threadIdx.x;
  const int e = t >> 2;
  if (e >= nedges) return;
  const int g = (t & 3) * 4;
  const int s = src[e];
  const int d = dst[e];
  const float4 v = *(const float4*)&vals[(size_t)s * 16 + g];
  const int4 ix = *(const int4*)&idx[(size_t)s * 16 + g];
  float* out = &H[(size_t)d * 128];
  atomicAdd(out + ix.x, v.x);
  atomicAdd(out + ix.y, v.y);
  atomicAdd(out + ix.z, v.z);
  atomicAdd(out + ix.w, v.w);
}

// ---------------------------------------------------------------------------
extern "C" void kernel_launch(void* const* d_in, const int* in_sizes, int n_in,
                              void* d_out, int out_size, void* d_ws,
                              size_t ws_size, hipStream_t stream) {
  const float* x = (const float*)d_in[0];
  const int* src = (const int*)d_in[1];
  const int* dst = (const int*)d_in[2];
  const float* W_in = (const float*)d_in[3];
  const float* b_in = (const float*)d_in[4];
  const float* W_lin = (const float*)d_in[5];
  const float* b_lin = (const float*)d_in[6];
  const float* eps = (const float*)d_in[7];
  const float* W_out = (const float*)d_in[8];
  const float* b_out = (const float*)d_in[9];
  float* out = (float*)d_out;

  const int n = in_sizes[0] / 128;
  const int E = in_sizes[1];

  float* A = (float*)d_ws;                  // dense h buffer      (n*128 f32)
  float* B = A + (size_t)n * 128;           // gemm temp           (n*128 f32)
  float* vals = B + (size_t)n * 128;        // compressed top-k    (n*16 f32)
  int* idx = (int*)(vals + (size_t)n * 16); // compressed indices  (n*16 i32)

  const int tiles128 = (n + 31) / 32;
  const int tiles64 = (n + 63) / 64;
  const dim3 blk(256);

  // h = relu(x @ W_in + b_in)
  gemm_kernel<128, true><<<512, blk, 0, stream>>>(x, W_in, b_in, A, n, tiles128);

  for (int l = 0; l < 2; ++l) {
    // t = h @ W_lin[l] + b_lin[l]
    gemm_kernel<128, false><<<512, blk, 0, stream>>>(
        A, W_lin + (size_t)l * 128 * 128, b_lin + (size_t)l * 128, B, n,
        tiles128);
    // top-16: compressed (vals, idx); A seeded with (1+eps)*h_sparse
    maxk_kernel<<<2048, blk, 0, stream>>>(B, eps + l, vals, idx, A, n);
    // A[dst] += h_sparse[src]
    scatter_kernel<<<(E * 4 + 255) / 256, blk, 0, stream>>>(src, dst, vals,
                                                            idx, A, E);
  }

  // out = h @ W_out + b_out
  gemm_kernel<64, false><<<512, blk, 0, stream>>>(A, W_out, b_out, out, n,
                                                  tiles64);
}

// Round 2
// 952.727 us; speedup vs baseline: 2.7693x; 2.7693x over previous
//
#include <hip/hip_runtime.h>
#include <cstdint>
#include <cstddef>

// ---------------------------------------------------------------------------
// MaxK-GIN: h=relu(x@W_in+b); 2x { h=h@W+b; maxk16; neigh=sum_in(h_sparse);
//           h=(1+eps)*h_sparse+neigh }; out = h@W_out+b_out
// Aggregation via device-built dst-CSR + LDS-accumulated gather (no global
// fp32 atomics — round-1 scatter was 7x write-amplified RMW-bound).
// ---------------------------------------------------------------------------

// ---------------- GEMM: Y[r, 0:NOUT] = X[r, 0:128] @ W + bias (opt relu) ----
template <int NOUT, bool RELU>
__global__ __launch_bounds__(256, 2) void gemm_kernel(
    const float* __restrict__ X, const float* __restrict__ W,
    const float* __restrict__ bias, float* __restrict__ Y, int nrows,
    int ntiles) {
  constexpr int CT = NOUT / 4;
  constexpr int RG = 256 / CT;
  constexpr int RPB = RG * 4;
  constexpr int XPAD = (NOUT == 64) ? 4 : 0;
  constexpr int XLD = 128 + XPAD;

  __shared__ float Wlds[128 * NOUT];
  __shared__ float Xlds[RPB * XLD];

  const int tid = threadIdx.x;

  for (int f = tid; f < 128 * NOUT / 4; f += 256) {
    ((float4*)Wlds)[f] = ((const float4*)W)[f];
  }

  const int c4 = (tid % CT) * 4;
  const int r0 = (tid / CT) * 4;
  const float4 bv = *(const float4*)&bias[c4];

  for (int tile = blockIdx.x; tile < ntiles; tile += gridDim.x) {
    const int row0 = tile * RPB;
    __syncthreads();

    for (int f = tid; f < RPB * 32; f += 256) {
      const int r = f >> 5;
      const int cq = (f & 31) * 4;
      const int grow = row0 + r;
      float4 xv = make_float4(0.f, 0.f, 0.f, 0.f);
      if (grow < nrows) xv = *(const float4*)&X[(size_t)grow * 128 + cq];
      *(float4*)&Xlds[r * XLD + cq] = xv;
    }
    __syncthreads();

    float4 acc[4];
#pragma unroll
    for (int j = 0; j < 4; ++j) acc[j] = make_float4(0.f, 0.f, 0.f, 0.f);

#pragma unroll 4
    for (int k = 0; k < 128; k += 4) {
      const float4 w0 = *(const float4*)&Wlds[(k + 0) * NOUT + c4];
      const float4 w1 = *(const float4*)&Wlds[(k + 1) * NOUT + c4];
      const float4 w2 = *(const float4*)&Wlds[(k + 2) * NOUT + c4];
      const float4 w3 = *(const float4*)&Wlds[(k + 3) * NOUT + c4];
#pragma unroll
      for (int j = 0; j < 4; ++j) {
        const float4 xv = *(const float4*)&Xlds[(r0 + j) * XLD + k];
        acc[j].x += xv.x * w0.x + xv.y * w1.x + xv.z * w2.x + xv.w * w3.x;
        acc[j].y += xv.x * w0.y + xv.y * w1.y + xv.z * w2.y + xv.w * w3.y;
        acc[j].z += xv.x * w0.z + xv.y * w1.z + xv.z * w2.z + xv.w * w3.z;
        acc[j].w += xv.x * w0.w + xv.y * w1.w + xv.z * w2.w + xv.w * w3.w;
      }
    }

#pragma unroll
    for (int j = 0; j < 4; ++j) {
      const int grow = row0 + r0 + j;
      if (grow < nrows) {
        float4 o = acc[j];
        o.x += bv.x; o.y += bv.y; o.z += bv.z; o.w += bv.w;
        if (RELU) {
          o.x = fmaxf(o.x, 0.f); o.y = fmaxf(o.y, 0.f);
          o.z = fmaxf(o.z, 0.f); o.w = fmaxf(o.w, 0.f);
        }
        *(float4*)&Y[(size_t)grow * NOUT + c4] = o;
      }
    }
  }
}

// ---------------- MaxK: top-16 of 128 per row -> compressed (vals, idx) -----
__global__ __launch_bounds__(256) void maxk_kernel(
    const float* __restrict__ T, float* __restrict__ vals,
    int* __restrict__ idxo, int nrows) {
  const int lane = threadIdx.x & 63;
  const int wid = threadIdx.x >> 6;

  for (int row = blockIdx.x * 4 + wid; row < nrows; row += gridDim.x * 4) {
    float v0 = T[(size_t)row * 128 + lane];
    float v1 = T[(size_t)row * 128 + 64 + lane];

#pragma unroll
    for (int it = 0; it < 16; ++it) {
      float m = fmaxf(v0, v1);
#pragma unroll
      for (int off = 32; off; off >>= 1) m = fmaxf(m, __shfl_xor(m, off));
      const unsigned long long b0 = __ballot(v0 == m);
      int sel;
      if (b0) {
        sel = __ffsll(b0) - 1;
        if (lane == sel) v0 = -INFINITY;
      } else {
        const unsigned long long b1 = __ballot(v1 == m);
        sel = __ffsll(b1) - 1;
        if (lane == sel) v1 = -INFINITY;
        sel += 64;
      }
      if (lane == 0) {
        vals[(size_t)row * 16 + it] = m;
        idxo[(size_t)row * 16 + it] = sel;
      }
    }
  }
}

// ---------------- CSR build ------------------------------------------------
__global__ __launch_bounds__(256) void hist_kernel(const int* __restrict__ dst,
                                                   int* __restrict__ deg,
                                                   int E) {
  const int e = blockIdx.x * 256 + threadIdx.x;
  if (e < E) atomicAdd(&deg[dst[e]], 1);
}

// per-block (1024 elems) exclusive scan; writes block totals
__global__ __launch_bounds__(256) void scan1_kernel(
    const int* __restrict__ deg, int* __restrict__ out,
    int* __restrict__ bsums, int n) {
  __shared__ int wsum[4];
  const int t = threadIdx.x;
  const int base = blockIdx.x * 1024 + t * 4;
  int d0 = 0, d1 = 0, d2 = 0, d3 = 0;
  if (base + 0 < n) d0 = deg[base + 0];
  if (base + 1 < n) d1 = deg[base + 1];
  if (base + 2 < n) d2 = deg[base + 2];
  if (base + 3 < n) d3 = deg[base + 3];
  const int s = d0 + d1 + d2 + d3;
  const int lane = t & 63, wid = t >> 6;
  int incl = s;
#pragma unroll
  for (int off = 1; off < 64; off <<= 1) {
    int u = __shfl_up(incl, off);
    if (lane >= off) incl += u;
  }
  if (lane == 63) wsum[wid] = incl;
  __syncthreads();
  int woff = 0;
  for (int w = 0; w < wid; ++w) woff += wsum[w];
  const int excl = woff + incl - s;
  if (base + 0 < n) out[base + 0] = excl;
  if (base + 1 < n) out[base + 1] = excl + d0;
  if (base + 2 < n) out[base + 2] = excl + d0 + d1;
  if (base + 3 < n) out[base + 3] = excl + d0 + d1 + d2;
  if (t == 255) bsums[blockIdx.x] = woff + incl;
}

__global__ void scan2_kernel(int* __restrict__ bsums, int nb) {
  if (threadIdx.x == 0 && blockIdx.x == 0) {
    int acc = 0;
    for (int i = 0; i < nb; ++i) {
      const int v = bsums[i];
      bsums[i] = acc;
      acc += v;
    }
  }
}

__global__ __launch_bounds__(256) void scan3_kernel(
    int* __restrict__ rs, int* __restrict__ cursor,
    const int* __restrict__ bsums, int n, int E) {
  const int i = blockIdx.x * 256 + threadIdx.x;
  if (i < n) {
    const int v = rs[i] + bsums[i >> 10];
    rs[i] = v;
    cursor[i] = v;
  }
  if (i == n) rs[n] = E;
}

__global__ __launch_bounds__(256) void fill_kernel(
    const int* __restrict__ src, const int* __restrict__ dst,
    int* __restrict__ cursor, int* __restrict__ csr_src, int E) {
  const int e = blockIdx.x * 256 + threadIdx.x;
  if (e < E) {
    const int pos = atomicAdd(&cursor[dst[e]], 1);
    csr_src[pos] = src[e];
  }
}

// ---------------- Gather: H[d] = (1+eps)*sparse[d] + sum_in sparse[src] -----
// one wave per dst row; wave-private LDS row; LDS atomics only.
__global__ __launch_bounds__(256) void gather_kernel(
    const int* __restrict__ rs, const int* __restrict__ csr_src,
    const float* __restrict__ vals, const int* __restrict__ idx,
    const float* __restrict__ eps_p, float* __restrict__ H, int nrows) {
  __shared__ float rowbuf[4][128];
  const int lane = threadIdx.x & 63;
  const int wid = threadIdx.x >> 6;
  const float e1 = 1.0f + *eps_p;
  float* row = rowbuf[wid];

  const int r = blockIdx.x * 4 + wid;
  if (r >= nrows) return;

  row[lane] = 0.f;
  row[lane + 64] = 0.f;

  const int beg = rs[r], end = rs[r + 1];
  const int sub = lane >> 4;   // which of 4 concurrent edges
  const int p = lane & 15;     // which nnz pair

  for (int b = beg; b < end; b += 4) {
    const int eidx = b + sub;
    if (eidx < end) {
      const int s = csr_src[eidx];
      const float v = vals[(size_t)s * 16 + p];
      const int id = idx[(size_t)s * 16 + p];
      atomicAdd(&row[id], v);
    }
  }
  // self term: (1+eps) * h_sparse[r]
  if (lane < 16) {
    const float v = vals[(size_t)r * 16 + lane];
    const int id = idx[(size_t)r * 16 + lane];
    atomicAdd(&row[id], e1 * v);
  }
  // same-wave DS ops are in-order; write dense result
  H[(size_t)r * 128 + lane] = row[lane];
  H[(size_t)r * 128 + 64 + lane] = row[lane + 64];
}

// ---------------------------------------------------------------------------
extern "C" void kernel_launch(void* const* d_in, const int* in_sizes, int n_in,
                              void* d_out, int out_size, void* d_ws,
                              size_t ws_size, hipStream_t stream) {
  const float* x = (const float*)d_in[0];
  const int* src = (const int*)d_in[1];
  const int* dst = (const int*)d_in[2];
  const float* W_in = (const float*)d_in[3];
  const float* b_in = (const float*)d_in[4];
  const float* W_lin = (const float*)d_in[5];
  const float* b_lin = (const float*)d_in[6];
  const float* eps = (const float*)d_in[7];
  const float* W_out = (const float*)d_in[8];
  const float* b_out = (const float*)d_in[9];
  float* out = (float*)d_out;

  const int n = in_sizes[0] / 128;
  const int E = in_sizes[1];

  char* w = (char*)d_ws;
  float* A = (float*)w;               w += (size_t)n * 128 * 4;
  float* B = (float*)w;               w += (size_t)n * 128 * 4;
  float* vals = (float*)w;            w += (size_t)n * 16 * 4;
  int* idx = (int*)w;                 w += (size_t)n * 16 * 4;
  int* deg = (int*)w;                 w += (size_t)n * 4;
  int* rs = (int*)w;                  w += (size_t)(n + 1) * 4;
  int* cursor = (int*)w;              w += (size_t)n * 4;
  int* bsums = (int*)w;               w += 1024 * 4;
  int* csr_src = (int*)w;             w += (size_t)E * 4;

  const int tiles128 = (n + 31) / 32;
  const int tiles64 = (n + 63) / 64;
  const int nb = (n + 1023) / 1024;
  const dim3 blk(256);

  // ---- CSR build (dst is call-invariant within the launch) ----
  hipMemsetAsync(deg, 0, (size_t)n * 4, stream);
  hist_kernel<<<(E + 255) / 256, blk, 0, stream>>>(dst, deg, E);
  scan1_kernel<<<nb, blk, 0, stream>>>(deg, rs, bsums, n);
  scan2_kernel<<<1, 64, 0, stream>>>(bsums, nb);
  scan3_kernel<<<(n + 256) / 256, blk, 0, stream>>>(rs, cursor, bsums, n, E);
  fill_kernel<<<(E + 255) / 256, blk, 0, stream>>>(src, dst, cursor, csr_src, E);

  // ---- h = relu(x @ W_in + b_in) ----
  gemm_kernel<128, true><<<512, blk, 0, stream>>>(x, W_in, b_in, A, n, tiles128);

  for (int l = 0; l < 2; ++l) {
    gemm_kernel<128, false><<<512, blk, 0, stream>>>(
        A, W_lin + (size_t)l * 128 * 128, b_lin + (size_t)l * 128, B, n,
        tiles128);
    maxk_kernel<<<2048, blk, 0, stream>>>(B, vals, idx, n);
    gather_kernel<<<(n + 3) / 4, blk, 0, stream>>>(rs, csr_src, vals, idx,
                                                   eps + l, A, n);
  }

  gemm_kernel<64, false><<<512, blk, 0, stream>>>(A, W_out, b_out, out, n,
                                                  tiles64);
}

// Round 3
// 900.491 us; speedup vs baseline: 2.9300x; 1.0580x over previous
//
#include <hip/hip_runtime.h>
#include <cstdint>
#include <cstddef>

// ---------------------------------------------------------------------------
// MaxK-GIN: h=relu(x@W_in+b); 2x { h=h@W+b; maxk16; neigh=sum_in(h_sparse);
//           h=(1+eps)*h_sparse+neigh }; out = h@W_out+b_out
// GEMMs: split-bf16 (hi+lo) MFMA, 3 products => ~fp32 accuracy at MFMA rate.
// Aggregation: dst-CSR + LDS-accumulated gather (no global fp32 atomics).
// ---------------------------------------------------------------------------

typedef __attribute__((ext_vector_type(8))) short bf16x8;
typedef __attribute__((ext_vector_type(4))) float f32x4;

__device__ __forceinline__ unsigned rne_bf16(float v) {
  unsigned u = __float_as_uint(v);
  return (u + 0x7fffu + ((u >> 16) & 1u)) >> 16;
}

// ---------------- W^T build: W[k][n] fp32 -> WtH/WtL[n][k] bf16 -------------
__global__ __launch_bounds__(256) void wt_build_kernel(
    const float* __restrict__ W, int nout, short* __restrict__ H,
    short* __restrict__ L) {
  const int i = blockIdx.x * 256 + threadIdx.x;  // i = n*128 + k
  if (i >= nout * 128) return;
  const int nn = i >> 7, k = i & 127;
  const float v = W[k * nout + nn];
  const unsigned hb = rne_bf16(v);
  const float hf = __uint_as_float(hb << 16);
  const unsigned lb = rne_bf16(v - hf);
  H[i] = (short)hb;
  L[i] = (short)lb;
}

// ---------------- MFMA GEMM: Y = X[.,128] @ W + bias (opt relu) -------------
// block: 256 thr / 4 waves; tile 64 rows x NOUT. W^T hi/lo in LDS (padded).
template <int NOUT, bool RELU>
__global__ __launch_bounds__(256, 2) void mfma_gemm_kernel(
    const float* __restrict__ X, const short* __restrict__ WtH,
    const short* __restrict__ WtL, const float* __restrict__ bias,
    float* __restrict__ Y, int nrows) {
  constexpr int NT = NOUT / 16;        // n-tiles per wave
  constexpr int LDB = 128 * 2 + 16;    // LDS row stride (bytes), +16B pad
  constexpr int PLANE = NOUT * LDB;
  __shared__ char lds[2 * PLANE];

  const int tid = threadIdx.x;
  // stage WtH/WtL -> LDS (coalesced b128 reads, padded rows)
  for (int u = tid; u < 2 * NOUT * 16; u += 256) {
    const int plane = u / (NOUT * 16);
    const int v = u % (NOUT * 16);
    const int nrow = v >> 4, seg = v & 15;
    const short* src = plane ? WtL : WtH;
    const float4 d = *(const float4*)&src[nrow * 128 + seg * 8];
    *(float4*)&lds[plane * PLANE + nrow * LDB + seg * 16] = d;
  }
  __syncthreads();

  const int lane = tid & 63;
  const int wv = tid >> 6;
  const int li = lane & 15;
  const int kg = lane >> 4;  // 0..3
  const int row = blockIdx.x * 64 + wv * 16 + li;
  const int rowc = (row < nrows) ? row : (nrows - 1);
  const float* xrow = X + (size_t)rowc * 128;

  f32x4 acc[NT];
#pragma unroll
  for (int t = 0; t < NT; ++t) acc[t] = (f32x4){0.f, 0.f, 0.f, 0.f};

#pragma unroll
  for (int c = 0; c < 4; ++c) {
    const float4 p0 = *(const float4*)&xrow[c * 32 + kg * 8];
    const float4 p1 = *(const float4*)&xrow[c * 32 + kg * 8 + 4];
    float f[8] = {p0.x, p0.y, p0.z, p0.w, p1.x, p1.y, p1.z, p1.w};
    bf16x8 ah, al;
#pragma unroll
    for (int e = 0; e < 8; ++e) {
      const unsigned hb = rne_bf16(f[e]);
      const float hf = __uint_as_float(hb << 16);
      const unsigned lb = rne_bf16(f[e] - hf);
      ah[e] = (short)hb;
      al[e] = (short)lb;
    }
    const int kb = c * 64 + kg * 16;
#pragma unroll
    for (int t = 0; t < NT; ++t) {
      const int boff = (t * 16 + li) * LDB + kb;
      const bf16x8 bh = *(const bf16x8*)&lds[boff];
      const bf16x8 bl = *(const bf16x8*)&lds[PLANE + boff];
      acc[t] = __builtin_amdgcn_mfma_f32_16x16x32_bf16(al, bh, acc[t], 0, 0, 0);
      acc[t] = __builtin_amdgcn_mfma_f32_16x16x32_bf16(ah, bl, acc[t], 0, 0, 0);
      acc[t] = __builtin_amdgcn_mfma_f32_16x16x32_bf16(ah, bh, acc[t], 0, 0, 0);
    }
  }

  // D layout (m89-verified): col = lane&15, row = (lane>>4)*4 + reg
  const int orow = blockIdx.x * 64 + wv * 16 + kg * 4;
#pragma unroll
  for (int t = 0; t < NT; ++t) {
    const int col = t * 16 + li;
    const float bv = bias[col];
#pragma unroll
    for (int r = 0; r < 4; ++r) {
      const int rr = orow + r;
      if (rr < nrows) {
        float o = acc[t][r] + bv;
        if (RELU) o = fmaxf(o, 0.f);
        Y[(size_t)rr * NOUT + col] = o;
      }
    }
  }
}

// ---------------- MaxK: top-16 of 128 per row -> compressed (vals, idx) -----
__global__ __launch_bounds__(256) void maxk_kernel(
    const float* __restrict__ T, float* __restrict__ vals,
    int* __restrict__ idxo, int nrows) {
  const int lane = threadIdx.x & 63;
  const int wid = threadIdx.x >> 6;

  for (int row = blockIdx.x * 4 + wid; row < nrows; row += gridDim.x * 4) {
    float v0 = T[(size_t)row * 128 + lane];
    float v1 = T[(size_t)row * 128 + 64 + lane];

#pragma unroll
    for (int it = 0; it < 16; ++it) {
      float m = fmaxf(v0, v1);
#pragma unroll
      for (int off = 32; off; off >>= 1) m = fmaxf(m, __shfl_xor(m, off));
      const unsigned long long b0 = __ballot(v0 == m);
      int sel;
      if (b0) {
        sel = __ffsll(b0) - 1;
        if (lane == sel) v0 = -INFINITY;
      } else {
        const unsigned long long b1 = __ballot(v1 == m);
        sel = __ffsll(b1) - 1;
        if (lane == sel) v1 = -INFINITY;
        sel += 64;
      }
      if (lane == 0) {
        vals[(size_t)row * 16 + it] = m;
        idxo[(size_t)row * 16 + it] = sel;
      }
    }
  }
}

// ---------------- CSR build ------------------------------------------------
__global__ __launch_bounds__(256) void hist_kernel(const int* __restrict__ dst,
                                                   int* __restrict__ deg,
                                                   int E) {
  const int e = blockIdx.x * 256 + threadIdx.x;
  if (e < E) atomicAdd(&deg[dst[e]], 1);
}

__global__ __launch_bounds__(256) void scan1_kernel(
    const int* __restrict__ deg, int* __restrict__ out,
    int* __restrict__ bsums, int n) {
  __shared__ int wsum[4];
  const int t = threadIdx.x;
  const int base = blockIdx.x * 1024 + t * 4;
  int d0 = 0, d1 = 0, d2 = 0, d3 = 0;
  if (base + 0 < n) d0 = deg[base + 0];
  if (base + 1 < n) d1 = deg[base + 1];
  if (base + 2 < n) d2 = deg[base + 2];
  if (base + 3 < n) d3 = deg[base + 3];
  const int s = d0 + d1 + d2 + d3;
  const int lane = t & 63, wid = t >> 6;
  int incl = s;
#pragma unroll
  for (int off = 1; off < 64; off <<= 1) {
    int u = __shfl_up(incl, off);
    if (lane >= off) incl += u;
  }
  if (lane == 63) wsum[wid] = incl;
  __syncthreads();
  int woff = 0;
  for (int w = 0; w < wid; ++w) woff += wsum[w];
  const int excl = woff + incl - s;
  if (base + 0 < n) out[base + 0] = excl;
  if (base + 1 < n) out[base + 1] = excl + d0;
  if (base + 2 < n) out[base + 2] = excl + d0 + d1;
  if (base + 3 < n) out[base + 3] = excl + d0 + d1 + d2;
  if (t == 255) bsums[blockIdx.x] = woff + incl;
}

// single-wave scan over block sums (nb <= 128)
__global__ __launch_bounds__(64) void scan2_kernel(int* __restrict__ bsums,
                                                   int nb) {
  const int lane = threadIdx.x;
  const int a = (lane < nb) ? bsums[lane] : 0;
  const int b = (lane + 64 < nb) ? bsums[lane + 64] : 0;
  int ia = a, ib = b;
#pragma unroll
  for (int off = 1; off < 64; off <<= 1) {
    const int ta = __shfl_up(ia, off);
    const int tb = __shfl_up(ib, off);
    if (lane >= off) { ia += ta; ib += tb; }
  }
  const int totA = __shfl(ia, 63);
  if (lane < nb) bsums[lane] = ia - a;
  if (lane + 64 < nb) bsums[lane + 64] = totA + ib - b;
}

__global__ __launch_bounds__(256) void scan3_kernel(
    int* __restrict__ rs, int* __restrict__ cursor,
    const int* __restrict__ bsums, int n, int E) {
  const int i = blockIdx.x * 256 + threadIdx.x;
  if (i < n) {
    const int v = rs[i] + bsums[i >> 10];
    rs[i] = v;
    cursor[i] = v;
  }
  if (i == n) rs[n] = E;
}

__global__ __launch_bounds__(256) void fill_kernel(
    const int* __restrict__ src, const int* __restrict__ dst,
    int* __restrict__ cursor, int* __restrict__ csr_src, int E) {
  const int e = blockIdx.x * 256 + threadIdx.x;
  if (e < E) {
    const int pos = atomicAdd(&cursor[dst[e]], 1);
    csr_src[pos] = src[e];
  }
}

// ---------------- Gather: H[d] = (1+eps)*sparse[d] + sum_in sparse[src] -----
__global__ __launch_bounds__(256) void gather_kernel(
    const int* __restrict__ rs, const int* __restrict__ csr_src,
    const float* __restrict__ vals, const int* __restrict__ idx,
    const float* __restrict__ eps_p, float* __restrict__ H, int nrows) {
  __shared__ float rowbuf[4][128];
  const int lane = threadIdx.x & 63;
  const int wid = threadIdx.x >> 6;
  const float e1 = 1.0f + *eps_p;
  float* row = rowbuf[wid];

  const int r = blockIdx.x * 4 + wid;
  if (r >= nrows) return;

  row[lane] = 0.f;
  row[lane + 64] = 0.f;

  const int beg = rs[r], end = rs[r + 1];
  const int sub = lane >> 4;
  const int p = lane & 15;

  for (int b = beg; b < end; b += 4) {
    const int eidx = b + sub;
    if (eidx < end) {
      const int s = csr_src[eidx];
      const float v = vals[(size_t)s * 16 + p];
      const int id = idx[(size_t)s * 16 + p];
      atomicAdd(&row[id], v);
    }
  }
  if (lane < 16) {
    const float v = vals[(size_t)r * 16 + lane];
    const int id = idx[(size_t)r * 16 + lane];
    atomicAdd(&row[id], e1 * v);
  }
  H[(size_t)r * 128 + lane] = row[lane];
  H[(size_t)r * 128 + 64 + lane] = row[lane + 64];
}

// ---------------------------------------------------------------------------
extern "C" void kernel_launch(void* const* d_in, const int* in_sizes, int n_in,
                              void* d_out, int out_size, void* d_ws,
                              size_t ws_size, hipStream_t stream) {
  const float* x = (const float*)d_in[0];
  const int* src = (const int*)d_in[1];
  const int* dst = (const int*)d_in[2];
  const float* W_in = (const float*)d_in[3];
  const float* b_in = (const float*)d_in[4];
  const float* W_lin = (const float*)d_in[5];
  const float* b_lin = (const float*)d_in[6];
  const float* eps = (const float*)d_in[7];
  const float* W_out = (const float*)d_in[8];
  const float* b_out = (const float*)d_in[9];
  float* out = (float*)d_out;

  const int n = in_sizes[0] / 128;
  const int E = in_sizes[1];

  char* w = (char*)d_ws;
  float* A = (float*)w;               w += (size_t)n * 128 * 4;
  float* B = (float*)w;               w += (size_t)n * 128 * 4;
  float* vals = (float*)w;            w += (size_t)n * 16 * 4;
  int* idx = (int*)w;                 w += (size_t)n * 16 * 4;
  int* deg = (int*)w;                 w += (size_t)n * 4;
  int* rs = (int*)w;                  w += (size_t)(n + 1) * 4;
  int* cursor = (int*)w;              w += (size_t)n * 4;
  int* bsums = (int*)w;               w += 1024 * 4;
  int* csr_src = (int*)w;             w += (size_t)E * 4;
  short* wtH = (short*)w;             w += (size_t)128 * 128 * 2;
  short* wtL = (short*)w;             w += (size_t)128 * 128 * 2;

  const int nb = (n + 1023) / 1024;
  const int gblocks = (n + 63) / 64;
  const dim3 blk(256);

  // ---- CSR build ----
  hipMemsetAsync(deg, 0, (size_t)n * 4, stream);
  hist_kernel<<<(E + 255) / 256, blk, 0, stream>>>(dst, deg, E);
  scan1_kernel<<<nb, blk, 0, stream>>>(deg, rs, bsums, n);
  scan2_kernel<<<1, 64, 0, stream>>>(bsums, nb);
  scan3_kernel<<<(n + 256) / 256, blk, 0, stream>>>(rs, cursor, bsums, n, E);
  fill_kernel<<<(E + 255) / 256, blk, 0, stream>>>(src, dst, cursor, csr_src, E);

  // ---- h = relu(x @ W_in + b_in) ----
  wt_build_kernel<<<(128 * 128 + 255) / 256, blk, 0, stream>>>(W_in, 128, wtH,
                                                               wtL);
  mfma_gemm_kernel<128, true><<<gblocks, blk, 0, stream>>>(x, wtH, wtL, b_in,
                                                           A, n);

  for (int l = 0; l < 2; ++l) {
    wt_build_kernel<<<(128 * 128 + 255) / 256, blk, 0, stream>>>(
        W_lin + (size_t)l * 128 * 128, 128, wtH, wtL);
    mfma_gemm_kernel<128, false><<<gblocks, blk, 0, stream>>>(
        A, wtH, wtL, b_lin + (size_t)l * 128, B, n);
    maxk_kernel<<<2048, blk, 0, stream>>>(B, vals, idx, n);
    gather_kernel<<<(n + 3) / 4, blk, 0, stream>>>(rs, csr_src, vals, idx,
                                                   eps + l, A, n);
  }

  wt_build_kernel<<<(128 * 64 + 255) / 256, blk, 0, stream>>>(W_out, 64, wtH,
                                                              wtL);
  mfma_gemm_kernel<64, false><<<gblocks, blk, 0, stream>>>(A, wtH, wtL, b_out,
                                                           out, n);
}